// Round 1
// baseline (427.784 us; speedup 1.0000x reference)
//
#include <hip/hip_runtime.h>
#include <hip/hip_bf16.h>

// Problem: 2x 3-head GAT (E=2048, only batch 0 consumed) + 2-layer GCN each,
// log_softmax / leaky outputs. All fp32.
//
// exp(-30) for non-neighbors:
#define EXPN30 9.357622969e-14f

// K1: per-node features. h[c,d] for 6 (gat,head) combos, plus separable
// softmax factors e1,e2 and exp(e1),exp(0.2 e1),exp(e2),exp(0.2 e2).
// hcol: [36][2048] column-major (comp = gat*18 + head*6 + d)
// pack1/pack2: [18][2048]: comps 0..5 = e, 6..11 = exp(e), 12..17 = exp(0.2e)
__global__ __launch_bounds__(256) void k1_features(
    const float* __restrict__ node, const float* __restrict__ uv,
    const float* __restrict__ Wt1, const float* __restrict__ at1,
    const float* __restrict__ Wt2, const float* __restrict__ at2,
    float* __restrict__ hcol, float* __restrict__ pack1, float* __restrict__ pack2) {
  __shared__ float sW[576];
  __shared__ float sA[36];
  int g = blockIdx.x >> 3;                         // 0: node GAT (Y), 1: uv GAT (O)
  int e = ((blockIdx.x & 7) << 8) + threadIdx.x;   // node index 0..2047
  const float* W = g ? Wt2 : Wt1;
  const float* A = g ? at2 : at1;
  const float* x = (g ? uv : node) + e * 32;       // batch 0 only
  for (int idx = threadIdx.x; idx < 576; idx += 256) sW[idx] = W[idx];
  if (threadIdx.x < 36) sA[threadIdx.x] = A[threadIdx.x];
  __syncthreads();
  float xv[32];
#pragma unroll
  for (int i = 0; i < 32; ++i) xv[i] = x[i];
#pragma unroll
  for (int h = 0; h < 3; ++h) {
    float hv[6];
#pragma unroll
    for (int d = 0; d < 6; ++d) hv[d] = 0.f;
#pragma unroll
    for (int i = 0; i < 32; ++i)
#pragma unroll
      for (int d = 0; d < 6; ++d) hv[d] += xv[i] * sW[h * 192 + i * 6 + d];
    float e1 = 0.f, e2 = 0.f;
#pragma unroll
    for (int d = 0; d < 6; ++d) {
      e1 += hv[d] * sA[h * 12 + d];
      e2 += hv[d] * sA[h * 12 + 6 + d];
    }
    int c = g * 3 + h;
#pragma unroll
    for (int d = 0; d < 6; ++d) hcol[(g * 18 + h * 6 + d) * 2048 + e] = hv[d];
    pack1[c * 2048 + e] = e1;
    pack1[(6 + c) * 2048 + e] = __expf(e1);
    pack1[(12 + c) * 2048 + e] = __expf(0.2f * e1);
    pack2[c * 2048 + e] = e2;
    pack2[(6 + c) * 2048 + e] = __expf(e2);
    pack2[(12 + c) * 2048 + e] = __expf(0.2f * e2);
  }
}

// K2: rowsum[c][i] = sum_j exp(logits[i,j]); store 1/rowsum.
// Block = 8 rows; j chunked by 256 with pack2 staged in LDS.
__global__ __launch_bounds__(256) void k2_rowsum(
    const float* __restrict__ adj0, const float* __restrict__ pack1,
    const float* __restrict__ pack2, float* __restrict__ invrs) {
  __shared__ float sp2[18 * 256];
  __shared__ float sE1[48], sP1[48], sQ1[48];
  __shared__ float red[4][48];
  int i0 = blockIdx.x * 8;
  int tid = threadIdx.x;
  if (tid < 48) {
    int r = tid / 6, c = tid % 6;
    sE1[tid] = pack1[c * 2048 + i0 + r];
    sP1[tid] = pack1[(6 + c) * 2048 + i0 + r];
    sQ1[tid] = pack1[(12 + c) * 2048 + i0 + r];
  }
  float sums[48];
#pragma unroll
  for (int s = 0; s < 48; ++s) sums[s] = 0.f;
  for (int c0 = 0; c0 < 2048; c0 += 256) {
    __syncthreads();
    for (int idx = tid; idx < 18 * 256; idx += 256)
      sp2[idx] = pack2[(idx >> 8) * 2048 + c0 + (idx & 255)];
    __syncthreads();
    int j = c0 + tid;
    float e2v[6], p2v[6], q2v[6];
#pragma unroll
    for (int c = 0; c < 6; ++c) {
      e2v[c] = sp2[c * 256 + tid];
      p2v[c] = sp2[(6 + c) * 256 + tid];
      q2v[c] = sp2[(12 + c) * 256 + tid];
    }
#pragma unroll
    for (int r = 0; r < 8; ++r) {
      float adjv = adj0[(i0 + r) * 2048 + j];
#pragma unroll
      for (int c = 0; c < 6; ++c) {
        float e = sE1[r * 6 + c] + e2v[c];
        bool pos = e > 0.f;
        float a = pos ? sP1[r * 6 + c] : sQ1[r * 6 + c];
        float b = pos ? p2v[c] : q2v[c];
        float w = (adjv == 1.0f) ? a * b : EXPN30;
        sums[r * 6 + c] += w;
      }
    }
  }
#pragma unroll
  for (int s = 0; s < 48; ++s) {
    float v = sums[s];
    for (int off = 32; off > 0; off >>= 1) v += __shfl_down(v, off);
    sums[s] = v;
  }
  int lane = tid & 63, wid = tid >> 6;
  if (lane == 0)
    for (int s = 0; s < 48; ++s) red[wid][s] = sums[s];
  __syncthreads();
  if (tid < 48) {
    float tot = red[0][tid] + red[1][tid] + red[2][tid] + red[3][tid];
    int r = tid / 6, c = tid % 6;
    invrs[c * 2048 + i0 + r] = 1.0f / tot;
  }
}

// K3: h'[j, k] += sum_i w[i,j] * (h[i,k]/rowsum), k = gat*18+head*6+d.
// Grid: (8 j-tiles of 256) x (32 i-splits of 64). Thread = one j, acc[36].
__global__ __launch_bounds__(256) void k3_hprime(
    const float* __restrict__ adj0, const float* __restrict__ hcol,
    const float* __restrict__ pack1, const float* __restrict__ pack2,
    const float* __restrict__ invrs, float* __restrict__ hp) {
  __shared__ float sp1[18 * 64];   // e1/p1/q1 for 64 i
  __shared__ float sHS[36 * 64];   // scaled h, comp-major
  int tid = threadIdx.x;
  int j = blockIdx.x * 256 + tid;
  int i0 = blockIdx.y * 64;
  for (int idx = tid; idx < 18 * 64; idx += 256) {
    int comp = idx >> 6, ii = idx & 63;
    sp1[idx] = pack1[comp * 2048 + i0 + ii];
  }
  for (int idx = tid; idx < 36 * 64; idx += 256) {
    int k = idx >> 6, ii = idx & 63;
    int c6 = k / 6;  // gat*3+head
    sHS[idx] = hcol[k * 2048 + i0 + ii] * invrs[c6 * 2048 + i0 + ii];
  }
  float e2v[6], p2v[6], q2v[6];
#pragma unroll
  for (int c = 0; c < 6; ++c) {
    e2v[c] = pack2[c * 2048 + j];
    p2v[c] = pack2[(6 + c) * 2048 + j];
    q2v[c] = pack2[(12 + c) * 2048 + j];
  }
  float acc[36];
#pragma unroll
  for (int k = 0; k < 36; ++k) acc[k] = 0.f;
  __syncthreads();
  for (int ii = 0; ii < 64; ++ii) {
    float adjv = adj0[(i0 + ii) * 2048 + j];
#pragma unroll
    for (int c = 0; c < 6; ++c) {
      float e = sp1[c * 64 + ii] + e2v[c];
      bool pos = e > 0.f;
      float a = pos ? sp1[(6 + c) * 64 + ii] : sp1[(12 + c) * 64 + ii];
      float b = pos ? p2v[c] : q2v[c];
      float w = (adjv == 1.0f) ? a * b : EXPN30;
#pragma unroll
      for (int d = 0; d < 6; ++d) acc[c * 6 + d] += w * sHS[(c * 6 + d) * 64 + ii];
    }
  }
#pragma unroll
  for (int k = 0; k < 36; ++k) atomicAdd(&hp[j * 36 + k], acc[k]);
}

// K4: hcat = elu(h'), T[j][0:16] = hcatY @ Wg1, T[j][16:32] = hcatO @ Wo1
__global__ __launch_bounds__(256) void k4_T(
    const float* __restrict__ hp, const float* __restrict__ Wg1,
    const float* __restrict__ Wo1, float* __restrict__ T) {
  __shared__ float sWg[288], sWo[288];
  int tid = threadIdx.x;
  int j = blockIdx.x * 256 + tid;
  for (int idx = tid; idx < 288; idx += 256) {
    sWg[idx] = Wg1[idx];
    sWo[idx] = Wo1[idx];
  }
  __syncthreads();
  float hcY[18], hcO[18];
#pragma unroll
  for (int r = 0; r < 18; ++r) {
    float x = hp[j * 36 + r];
    hcY[r] = x > 0.f ? x : __expf(x) - 1.f;
    float y = hp[j * 36 + 18 + r];
    hcO[r] = y > 0.f ? y : __expf(y) - 1.f;
  }
  float ty[16], to[16];
#pragma unroll
  for (int c = 0; c < 16; ++c) { ty[c] = 0.f; to[c] = 0.f; }
#pragma unroll
  for (int r = 0; r < 18; ++r)
#pragma unroll
    for (int c = 0; c < 16; ++c) {
      ty[c] += hcY[r] * sWg[r * 16 + c];
      to[c] += hcO[r] * sWo[r * 16 + c];
    }
#pragma unroll
  for (int c = 0; c < 16; ++c) {
    T[j * 32 + c] = ty[c];
    T[j * 32 + 16 + c] = to[c];
  }
}

// K5: Craw = a0 @ T  ([2048x2048] @ [2048x32]), tiled, k-split + atomics.
// Grid (32 row-tiles, 8 k-segments). Thread: row = tid&63, colgroup = tid>>6.
__global__ __launch_bounds__(256) void k5_gcn1(
    const float* __restrict__ adj0, const float* __restrict__ T,
    float* __restrict__ Craw) {
  __shared__ float sAt[64 * 65];  // +1 pad
  __shared__ float sT[64 * 32];
  int tid = threadIdx.x;
  int row = tid & 63, cg = tid >> 6;
  int i0 = blockIdx.x * 64, k0 = blockIdx.y * 256;
  float acc[8];
#pragma unroll
  for (int t = 0; t < 8; ++t) acc[t] = 0.f;
  for (int ch = 0; ch < 4; ++ch) {
    int kb = k0 + ch * 64;
    __syncthreads();
    for (int idx = tid; idx < 4096; idx += 256) {
      int r = idx >> 6, k = idx & 63;
      sAt[r * 65 + k] = adj0[(i0 + r) * 2048 + kb + k];
    }
    for (int idx = tid; idx < 2048; idx += 256)
      sT[idx] = T[(kb + (idx >> 5)) * 32 + (idx & 31)];
    __syncthreads();
#pragma unroll 16
    for (int k = 0; k < 64; ++k) {
      float a = sAt[row * 65 + k];
      const float* tp = &sT[k * 32 + cg * 8];
#pragma unroll
      for (int t = 0; t < 8; ++t) acc[t] += a * tp[t];
    }
  }
#pragma unroll
  for (int t = 0; t < 8; ++t) atomicAdd(&Craw[(i0 + row) * 32 + cg * 8 + t], acc[t]);
}

// K6: bias+relu on Craw, then T2[j][4] = {relu(Y1)@Wg2 (2), relu(O1)@Wo2 (2)}
__global__ __launch_bounds__(256) void k6_T2(
    const float* __restrict__ Craw, const float* __restrict__ bg1,
    const float* __restrict__ Wg2, const float* __restrict__ bo1,
    const float* __restrict__ Wo2, float* __restrict__ T2) {
  int j = blockIdx.x * 256 + threadIdx.x;
  float y0 = 0.f, y1 = 0.f, o0 = 0.f, o1 = 0.f;
#pragma unroll
  for (int c = 0; c < 16; ++c) {
    float yv = Craw[j * 32 + c] + bg1[c];
    yv = yv > 0.f ? yv : 0.f;
    y0 += yv * Wg2[c * 2 + 0];
    y1 += yv * Wg2[c * 2 + 1];
    float ov = Craw[j * 32 + 16 + c] + bo1[c];
    ov = ov > 0.f ? ov : 0.f;
    o0 += ov * Wo2[c * 2 + 0];
    o1 += ov * Wo2[c * 2 + 1];
  }
  T2[j * 4 + 0] = y0;
  T2[j * 4 + 1] = y1;
  T2[j * 4 + 2] = o0;
  T2[j * 4 + 3] = o1;
}

// K7: final a0 @ T2 (+bias), log_softmax(axis=1) and leaky(0.01), write out.
// Block = 16 rows (4 waves x 4 rows each), full T2 staged in LDS (32 KB).
__global__ __launch_bounds__(256) void k7_final(
    const float* __restrict__ adj0, const float* __restrict__ T2,
    const float* __restrict__ bg2, const float* __restrict__ bo2,
    float* __restrict__ out) {
  __shared__ float4 sT2[2048];
  int tid = threadIdx.x;
  const float4* T24 = (const float4*)T2;
  for (int idx = tid; idx < 2048; idx += 256) sT2[idx] = T24[idx];
  __syncthreads();
  int lane = tid & 63, w = tid >> 6;
  for (int q = 0; q < 4; ++q) {
    int r = blockIdx.x * 16 + w * 4 + q;
    float4 acc = make_float4(0.f, 0.f, 0.f, 0.f);
    for (int k = lane; k < 2048; k += 64) {
      float a = adj0[r * 2048 + k];
      float4 t = sT2[k];
      acc.x += a * t.x;
      acc.y += a * t.y;
      acc.z += a * t.z;
      acc.w += a * t.w;
    }
    for (int off = 32; off > 0; off >>= 1) {
      acc.x += __shfl_down(acc.x, off);
      acc.y += __shfl_down(acc.y, off);
      acc.z += __shfl_down(acc.z, off);
      acc.w += __shfl_down(acc.w, off);
    }
    if (lane == 0) {
      float y0 = acc.x + bg2[0], y1 = acc.y + bg2[1];
      float m = fmaxf(y0, y1);
      float ls = m + logf(__expf(y0 - m) + __expf(y1 - m));
      out[r * 2 + 0] = y0 - ls;
      out[r * 2 + 1] = y1 - ls;
      float o0 = acc.z + bo2[0], o1 = acc.w + bo2[1];
      out[4096 + r * 2 + 0] = o0 > 0.f ? o0 : 0.01f * o0;
      out[4096 + r * 2 + 1] = o1 > 0.f ? o1 : 0.01f * o1;
    }
  }
}

extern "C" void kernel_launch(void* const* d_in, const int* in_sizes, int n_in,
                              void* d_out, int out_size, void* d_ws, size_t ws_size,
                              hipStream_t stream) {
  const float* node = (const float*)d_in[0];
  const float* uv = (const float*)d_in[1];
  const float* adj = (const float*)d_in[2];  // batch 0 = first 2048*2048
  const float* Wt1 = (const float*)d_in[3];
  const float* at1 = (const float*)d_in[4];
  const float* Wt2 = (const float*)d_in[5];
  const float* at2 = (const float*)d_in[6];
  const float* Wg1 = (const float*)d_in[7];
  const float* bg1 = (const float*)d_in[8];
  const float* Wg2 = (const float*)d_in[9];
  const float* bg2 = (const float*)d_in[10];
  const float* Wo1 = (const float*)d_in[11];
  const float* bo1 = (const float*)d_in[12];
  const float* Wo2 = (const float*)d_in[13];
  const float* bo2 = (const float*)d_in[14];
  float* ws = (float*)d_ws;
  float* hcol = ws;                 // 36*2048 = 73728
  float* pack1 = ws + 73728;        // 18*2048 = 36864
  float* pack2 = ws + 110592;       // 36864
  float* invrs = ws + 147456;       // 6*2048 = 12288
  float* hp = ws + 159744;          // 2048*36 = 73728 (zeroed)
  float* Craw = ws + 233472;        // 2048*32 = 65536 (zeroed)
  float* T = ws + 299008;           // 2048*32 = 65536
  float* T2 = ws + 364544;          // 2048*4  = 8192
  float* out = (float*)d_out;

  hipMemsetAsync(hp, 0, (73728 + 65536) * sizeof(float), stream);
  k1_features<<<16, 256, 0, stream>>>(node, uv, Wt1, at1, Wt2, at2, hcol, pack1, pack2);
  k2_rowsum<<<256, 256, 0, stream>>>(adj, pack1, pack2, invrs);
  k3_hprime<<<dim3(8, 32), 256, 0, stream>>>(adj, hcol, pack1, pack2, invrs, hp);
  k4_T<<<8, 256, 0, stream>>>(hp, Wg1, Wo1, T);
  k5_gcn1<<<dim3(32, 8), 256, 0, stream>>>(adj, T, Craw);
  k6_T2<<<8, 256, 0, stream>>>(Craw, bg1, Wg2, bo1, Wo2, T2);
  k7_final<<<128, 256, 0, stream>>>(adj, T2, bg2, bo2, out);
}

// Round 2
// 271.417 us; speedup vs baseline: 1.5761x; 1.5761x over previous
//
#include <hip/hip_runtime.h>
#include <hip/hip_bf16.h>

// GAT x2 (3 heads, E=2048, batch 0 only) + 2-layer GCN, log_softmax / leaky.
// exp(-30) for non-neighbors:
#define EXPN30 9.357622969e-14f

// ---------------------------------------------------------------------------
// K1: per-node features. hcol[36][2048] (comp = gat*18 + head*6 + d),
// pack1/pack2 [18][2048]: rows 0..5 = e, 6..11 = exp(e), 12..17 = exp(0.2e)
__global__ __launch_bounds__(256) void k1_features(
    const float* __restrict__ node, const float* __restrict__ uv,
    const float* __restrict__ Wt1, const float* __restrict__ at1,
    const float* __restrict__ Wt2, const float* __restrict__ at2,
    float* __restrict__ hcol, float* __restrict__ pack1, float* __restrict__ pack2) {
  __shared__ float sW[576];
  __shared__ float sA[36];
  int g = blockIdx.x >> 3;
  int e = ((blockIdx.x & 7) << 8) + threadIdx.x;
  const float* W = g ? Wt2 : Wt1;
  const float* A = g ? at2 : at1;
  const float* x = (g ? uv : node) + e * 32;
  for (int idx = threadIdx.x; idx < 576; idx += 256) sW[idx] = W[idx];
  if (threadIdx.x < 36) sA[threadIdx.x] = A[threadIdx.x];
  __syncthreads();
  float xv[32];
#pragma unroll
  for (int i = 0; i < 32; ++i) xv[i] = x[i];
#pragma unroll
  for (int h = 0; h < 3; ++h) {
    float hv[6];
#pragma unroll
    for (int d = 0; d < 6; ++d) hv[d] = 0.f;
#pragma unroll
    for (int i = 0; i < 32; ++i)
#pragma unroll
      for (int d = 0; d < 6; ++d) hv[d] += xv[i] * sW[h * 192 + i * 6 + d];
    float e1 = 0.f, e2 = 0.f;
#pragma unroll
    for (int d = 0; d < 6; ++d) {
      e1 += hv[d] * sA[h * 12 + d];
      e2 += hv[d] * sA[h * 12 + 6 + d];
    }
    int c = g * 3 + h;
#pragma unroll
    for (int d = 0; d < 6; ++d) hcol[(g * 18 + h * 6 + d) * 2048 + e] = hv[d];
    pack1[c * 2048 + e] = e1;
    pack1[(6 + c) * 2048 + e] = __expf(e1);
    pack1[(12 + c) * 2048 + e] = __expf(0.2f * e1);
    pack2[c * 2048 + e] = e2;
    pack2[(6 + c) * 2048 + e] = __expf(e2);
    pack2[(12 + c) * 2048 + e] = __expf(0.2f * e2);
  }
}

// ---------------------------------------------------------------------------
// K2: invrs[c][i] = 1 / sum_j exp(logits[i,j,c]).
// Block = 384 (6 waves; wave = comp c, lanes sweep j). 4 rows per block.
__global__ __launch_bounds__(384) void k2_rowsum(
    const float* __restrict__ adj0, const float* __restrict__ pack1,
    const float* __restrict__ pack2, float* __restrict__ invrs) {
  int tid = threadIdx.x;
  int c = tid >> 6, lane = tid & 63;
  int i0 = blockIdx.x * 4;
  float e1r[4], p1r[4], q1r[4], sum[4];
#pragma unroll
  for (int r = 0; r < 4; ++r) {
    e1r[r] = pack1[c * 2048 + i0 + r];
    p1r[r] = pack1[(6 + c) * 2048 + i0 + r];
    q1r[r] = pack1[(12 + c) * 2048 + i0 + r];
    sum[r] = 0.f;
  }
  for (int jc = 0; jc < 2048; jc += 64) {
    int j = jc + lane;
    float e2v = pack2[c * 2048 + j];
    float p2v = pack2[(6 + c) * 2048 + j];
    float q2v = pack2[(12 + c) * 2048 + j];
#pragma unroll
    for (int r = 0; r < 4; ++r) {
      float adjv = adj0[(i0 + r) * 2048 + j];
      float e = e1r[r] + e2v;
      bool pos = e > 0.f;
      float a = pos ? p1r[r] : q1r[r];
      float b = pos ? p2v : q2v;
      sum[r] += (adjv == 1.0f) ? a * b : EXPN30;
    }
  }
#pragma unroll
  for (int r = 0; r < 4; ++r) {
#pragma unroll
    for (int off = 32; off > 0; off >>= 1) sum[r] += __shfl_down(sum[r], off);
  }
  if (lane == 0) {
#pragma unroll
    for (int r = 0; r < 4; ++r) invrs[c * 2048 + i0 + r] = 1.0f / sum[r];
  }
}

// ---------------------------------------------------------------------------
// K3: hp_part[s][k][j] = sum_{i in split s} w(i,j,c) * (h[i,k]*invrs[c][i]).
// Block = 384 (wave = comp c, lanes = 64 j). Grid (32 j-tiles, nsplit).
// LDS: adj tile 64x64, per-i packs (e1,p1,q1), scaled h (6 per i, padded to 8).
__global__ __launch_bounds__(384) void k3_hprime(
    const float* __restrict__ adj0, const float* __restrict__ hcol,
    const float* __restrict__ pack1, const float* __restrict__ pack2,
    const float* __restrict__ invrs, float* __restrict__ hp_part, int ipers) {
  __shared__ float sAdj[64 * 64];
  __shared__ float4 sPack[6 * 64];   // e1, p1, q1, 0
  __shared__ float sHS[6 * 64 * 8];  // scaled h, 6 used + 2 pad
  float4* sAdj4 = (float4*)sAdj;
  const float4* adj4 = (const float4*)adj0;
  float4* sHS4 = (float4*)sHS;
  int tid = threadIdx.x;
  int c6 = tid >> 6, jl = tid & 63;
  int j0 = blockIdx.x * 64;
  int j = j0 + jl;
  int s = blockIdx.y;
  float e2v = pack2[c6 * 2048 + j];
  float p2v = pack2[(6 + c6) * 2048 + j];
  float q2v = pack2[(12 + c6) * 2048 + j];
  float acc0 = 0.f, acc1 = 0.f, acc2 = 0.f, acc3 = 0.f, acc4 = 0.f, acc5 = 0.f;
  int ibeg = s * ipers, iend = ibeg + ipers;
  for (int i0 = ibeg; i0 < iend; i0 += 64) {
    __syncthreads();
    // stage adj tile [64 i][64 j] via float4
    for (int idx = tid; idx < 1024; idx += 384) {
      int ii = idx >> 4, c4 = idx & 15;
      sAdj4[ii * 16 + c4] = adj4[(i0 + ii) * 512 + (j0 >> 2) + c4];
    }
    // stage per-i packs + scaled h: one (c, ii) per thread
    {
      int cc = c6, ii = jl;
      float e1 = pack1[cc * 2048 + i0 + ii];
      float p1 = pack1[(6 + cc) * 2048 + i0 + ii];
      float q1 = pack1[(12 + cc) * 2048 + i0 + ii];
      sPack[cc * 64 + ii] = make_float4(e1, p1, q1, 0.f);
      float iv = invrs[cc * 2048 + i0 + ii];
#pragma unroll
      for (int d = 0; d < 6; ++d)
        sHS[(cc * 64 + ii) * 8 + d] = hcol[(cc * 6 + d) * 2048 + i0 + ii] * iv;
      sHS[(cc * 64 + ii) * 8 + 6] = 0.f;
      sHS[(cc * 64 + ii) * 8 + 7] = 0.f;
    }
    __syncthreads();
#pragma unroll 8
    for (int ii = 0; ii < 64; ++ii) {
      float adjv = sAdj[ii * 64 + jl];
      float4 pk = sPack[c6 * 64 + ii];
      float4 h0 = sHS4[(c6 * 64 + ii) * 2];
      float4 h1 = sHS4[(c6 * 64 + ii) * 2 + 1];
      float e = pk.x + e2v;
      bool pos = e > 0.f;
      float a = pos ? pk.y : pk.z;
      float b = pos ? p2v : q2v;
      float w = (adjv == 1.0f) ? a * b : EXPN30;
      acc0 += w * h0.x;
      acc1 += w * h0.y;
      acc2 += w * h0.z;
      acc3 += w * h0.w;
      acc4 += w * h1.x;
      acc5 += w * h1.y;
    }
  }
  int kb = c6 * 6;
  hp_part[(s * 36 + kb + 0) * 2048 + j] = acc0;
  hp_part[(s * 36 + kb + 1) * 2048 + j] = acc1;
  hp_part[(s * 36 + kb + 2) * 2048 + j] = acc2;
  hp_part[(s * 36 + kb + 3) * 2048 + j] = acc3;
  hp_part[(s * 36 + kb + 4) * 2048 + j] = acc4;
  hp_part[(s * 36 + kb + 5) * 2048 + j] = acc5;
}

// ---------------------------------------------------------------------------
// K4: merge partials -> hp[j][36] in LDS, elu, then T[j][32] = {hcY@Wg1, hcO@Wo1}.
// Block 256, 64 j per block, grid 32. Thread = (jl, wq): wq picks gat + 8 cols.
__global__ __launch_bounds__(256) void k4_T(
    const float* __restrict__ hp_part, const float* __restrict__ Wg1,
    const float* __restrict__ Wo1, float* __restrict__ T, int nsplit) {
  __shared__ float sHP[64 * 37];  // stride 37: 5*jl mod 32 -> conflict-free
  __shared__ float sWg[288], sWo[288];
  int tid = threadIdx.x;
  int j0 = blockIdx.x * 64;
  for (int idx = tid; idx < 288; idx += 256) {
    sWg[idx] = Wg1[idx];
    sWo[idx] = Wo1[idx];
  }
  for (int idx = tid; idx < 2304; idx += 256) {
    int r = idx >> 6, jl = idx & 63;
    float s = 0.f;
    for (int sp = 0; sp < nsplit; ++sp)
      s += hp_part[(sp * 36 + r) * 2048 + j0 + jl];
    sHP[jl * 37 + r] = s;
  }
  __syncthreads();
  int jl = tid & 63, wq = tid >> 6;
  int gat = wq >> 1;
  int c0 = (wq & 1) * 8;
  const float* Wp = gat ? sWo : sWg;
  float acc[8];
#pragma unroll
  for (int t = 0; t < 8; ++t) acc[t] = 0.f;
#pragma unroll
  for (int r = 0; r < 18; ++r) {
    float x = sHP[jl * 37 + gat * 18 + r];
    float hc = x > 0.f ? x : __expf(x) - 1.f;
#pragma unroll
    for (int t = 0; t < 8; ++t) acc[t] += hc * Wp[r * 16 + c0 + t];
  }
#pragma unroll
  for (int t = 0; t < 8; ++t) T[(j0 + jl) * 32 + gat * 16 + c0 + t] = acc[t];
}

// ---------------------------------------------------------------------------
// K5: Craw = a0 @ T  ([2048x2048] @ [2048x32]), k-split + atomics.
__global__ __launch_bounds__(256) void k5_gcn1(
    const float* __restrict__ adj0, const float* __restrict__ T,
    float* __restrict__ Craw) {
  __shared__ float sAt[64 * 65];
  __shared__ float sT[64 * 32];
  int tid = threadIdx.x;
  int row = tid & 63, cg = tid >> 6;
  int i0 = blockIdx.x * 64, k0 = blockIdx.y * 256;
  float acc[8];
#pragma unroll
  for (int t = 0; t < 8; ++t) acc[t] = 0.f;
  for (int ch = 0; ch < 4; ++ch) {
    int kb = k0 + ch * 64;
    __syncthreads();
    for (int idx = tid; idx < 4096; idx += 256) {
      int r = idx >> 6, k = idx & 63;
      sAt[r * 65 + k] = adj0[(i0 + r) * 2048 + kb + k];
    }
    for (int idx = tid; idx < 2048; idx += 256)
      sT[idx] = T[(kb + (idx >> 5)) * 32 + (idx & 31)];
    __syncthreads();
#pragma unroll 16
    for (int k = 0; k < 64; ++k) {
      float a = sAt[row * 65 + k];
      const float* tp = &sT[k * 32 + cg * 8];
#pragma unroll
      for (int t = 0; t < 8; ++t) acc[t] += a * tp[t];
    }
  }
#pragma unroll
  for (int t = 0; t < 8; ++t) atomicAdd(&Craw[(i0 + row) * 32 + cg * 8 + t], acc[t]);
}

// ---------------------------------------------------------------------------
// K6: bias+relu on Craw, then T2[j][4] = {relu(Y1)@Wg2, relu(O1)@Wo2}
__global__ __launch_bounds__(256) void k6_T2(
    const float* __restrict__ Craw, const float* __restrict__ bg1,
    const float* __restrict__ Wg2, const float* __restrict__ bo1,
    const float* __restrict__ Wo2, float* __restrict__ T2) {
  int j = blockIdx.x * 256 + threadIdx.x;
  float y0 = 0.f, y1 = 0.f, o0 = 0.f, o1 = 0.f;
#pragma unroll
  for (int c = 0; c < 16; ++c) {
    float yv = Craw[j * 32 + c] + bg1[c];
    yv = yv > 0.f ? yv : 0.f;
    y0 += yv * Wg2[c * 2 + 0];
    y1 += yv * Wg2[c * 2 + 1];
    float ov = Craw[j * 32 + 16 + c] + bo1[c];
    ov = ov > 0.f ? ov : 0.f;
    o0 += ov * Wo2[c * 2 + 0];
    o1 += ov * Wo2[c * 2 + 1];
  }
  T2[j * 4 + 0] = y0;
  T2[j * 4 + 1] = y1;
  T2[j * 4 + 2] = o0;
  T2[j * 4 + 3] = o1;
}

// ---------------------------------------------------------------------------
// K7: final a0 @ T2 (+bias), log_softmax(axis=1) + leaky(0.01).
// Block = 8 rows (4 waves x 2 rows), full T2 (32 KB) in LDS. Grid 256.
__global__ __launch_bounds__(256) void k7_final(
    const float* __restrict__ adj0, const float* __restrict__ T2,
    const float* __restrict__ bg2, const float* __restrict__ bo2,
    float* __restrict__ out) {
  __shared__ float4 sT2[2048];
  int tid = threadIdx.x;
  const float4* T24 = (const float4*)T2;
  for (int idx = tid; idx < 2048; idx += 256) sT2[idx] = T24[idx];
  __syncthreads();
  int lane = tid & 63, w = tid >> 6;
  for (int q = 0; q < 2; ++q) {
    int r = blockIdx.x * 8 + w * 2 + q;
    float4 acc = make_float4(0.f, 0.f, 0.f, 0.f);
    for (int k = lane; k < 2048; k += 64) {
      float a = adj0[r * 2048 + k];
      float4 t = sT2[k];
      acc.x += a * t.x;
      acc.y += a * t.y;
      acc.z += a * t.z;
      acc.w += a * t.w;
    }
#pragma unroll
    for (int off = 32; off > 0; off >>= 1) {
      acc.x += __shfl_down(acc.x, off);
      acc.y += __shfl_down(acc.y, off);
      acc.z += __shfl_down(acc.z, off);
      acc.w += __shfl_down(acc.w, off);
    }
    if (lane == 0) {
      float y0 = acc.x + bg2[0], y1 = acc.y + bg2[1];
      float m = fmaxf(y0, y1);
      float ls = m + logf(__expf(y0 - m) + __expf(y1 - m));
      out[r * 2 + 0] = y0 - ls;
      out[r * 2 + 1] = y1 - ls;
      float o0 = acc.z + bo2[0], o1 = acc.w + bo2[1];
      out[4096 + r * 2 + 0] = o0 > 0.f ? o0 : 0.01f * o0;
      out[4096 + r * 2 + 1] = o1 > 0.f ? o1 : 0.01f * o1;
    }
  }
}

extern "C" void kernel_launch(void* const* d_in, const int* in_sizes, int n_in,
                              void* d_out, int out_size, void* d_ws, size_t ws_size,
                              hipStream_t stream) {
  const float* node = (const float*)d_in[0];
  const float* uv = (const float*)d_in[1];
  const float* adj = (const float*)d_in[2];  // batch 0 = first 2048*2048
  const float* Wt1 = (const float*)d_in[3];
  const float* at1 = (const float*)d_in[4];
  const float* Wt2 = (const float*)d_in[5];
  const float* at2 = (const float*)d_in[6];
  const float* Wg1 = (const float*)d_in[7];
  const float* bg1 = (const float*)d_in[8];
  const float* Wg2 = (const float*)d_in[9];
  const float* bg2 = (const float*)d_in[10];
  const float* Wo1 = (const float*)d_in[11];
  const float* bo1 = (const float*)d_in[12];
  const float* Wo2 = (const float*)d_in[13];
  const float* bo2 = (const float*)d_in[14];
  float* ws = (float*)d_ws;
  float* hcol = ws;                  // 36*2048 = 73728
  float* pack1 = ws + 73728;         // 36864
  float* pack2 = ws + 110592;        // 36864
  float* invrs = ws + 147456;        // 12288
  float* T = ws + 159744;            // 65536
  float* T2 = ws + 225280;           // 8192
  float* Craw = ws + 233472;         // 65536 (zeroed)
  float* hp_part = ws + 299008;      // nsplit * 73728
  float* out = (float*)d_out;

  // choose i-split count for k3 from available workspace (ws_size is constant
  // across calls -> deterministic)
  long avail = (long)(ws_size / 4) - 299008L;
  int nsplit = 1;
  if (avail >= 16L * 73728) nsplit = 16;
  else if (avail >= 8L * 73728) nsplit = 8;
  else if (avail >= 4L * 73728) nsplit = 4;
  else if (avail >= 2L * 73728) nsplit = 2;
  int ipers = 2048 / nsplit;

  hipMemsetAsync(Craw, 0, 65536 * sizeof(float), stream);
  k1_features<<<16, 256, 0, stream>>>(node, uv, Wt1, at1, Wt2, at2, hcol, pack1, pack2);
  k2_rowsum<<<512, 384, 0, stream>>>(adj, pack1, pack2, invrs);
  k3_hprime<<<dim3(32, nsplit), 384, 0, stream>>>(adj, hcol, pack1, pack2, invrs, hp_part, ipers);
  k4_T<<<32, 256, 0, stream>>>(hp_part, Wg1, Wo1, T, nsplit);
  k5_gcn1<<<dim3(32, 8), 256, 0, stream>>>(adj, T, Craw);
  k6_T2<<<8, 256, 0, stream>>>(Craw, bg1, Wg2, bo1, Wo2, T2);
  k7_final<<<256, 256, 0, stream>>>(adj, T2, bg2, bo2, out);
}